// Round 2
// baseline (517.575 us; speedup 1.0000x reference)
//
#include <hip/hip_runtime.h>
#include <stdint.h>

#define C_DIM 256
#define L_DIM 8192
#define B_DIM 8
#define CR 64
#define GK 112   // G*K = 16*7
#define KW 7

using short8  = __attribute__((ext_vector_type(8))) short;
using floatx4 = __attribute__((ext_vector_type(4))) float;

__device__ __forceinline__ unsigned short f2bf(float f) {
    union { float f; uint32_t u; } v; v.f = f;
    uint32_t u = v.u;
    uint32_t r = (u + 0x7fff + ((u >> 16) & 1)) >> 16;
    return (unsigned short)r;
}
__device__ __forceinline__ float bf2f(unsigned short h) {
    union { uint32_t u; float f; } v; v.u = ((uint32_t)h) << 16;
    return v.f;
}

// ---------------------------------------------------------------------------
// K0: weight prep.
//   wb   bf16 [512][256]  = [w_main ; w_skip]
//   wrT  f32  [256][64]   = w_reduce transposed (c-major)  -> s_load-friendly
//   wspT f32  [64][112]   = w_span transposed (r-major)    -> s_load-friendly
// ---------------------------------------------------------------------------
__global__ __launch_bounds__(256) void k0_prep(const float* __restrict__ wm,
                                               const float* __restrict__ wk,
                                               const float* __restrict__ wr,
                                               const float* __restrict__ wsp,
                                               unsigned short* __restrict__ wb,
                                               float* __restrict__ wrT,
                                               float* __restrict__ wspT) {
    int i = blockIdx.x * 256 + threadIdx.x;
    if (i < 131072) {
        float v = (i < 65536) ? wm[i] : wk[i - 65536];
        wb[i] = f2bf(v);
    } else if (i < 147456) {
        int j = i - 131072;          // j = c*64 + r
        int c = j >> 6, r = j & 63;
        wrT[j] = wr[r * C_DIM + c];
    } else if (i < 154624) {
        int j = i - 147456;          // j = r*112 + row
        int r = j / 112, row = j - r * 112;
        wspT[j] = wsp[row * CR + r];
    }
}

// ---------------------------------------------------------------------------
// KA: fused  h=relu(Wr@x) -> ker=Wsp@h -> involution -> PReLU -> LayerNorm
// One block = (b, 64-column tile). Writes xnt transposed bf16: [(b*L+l)][c].
// LDS: xsT stride 258 shorts (129 dwords == 1 mod 32 -> conflict-free both
// for consecutive-jj-lane access and consecutive-c-lane access).
// ---------------------------------------------------------------------------
#define XS_STR 258
#define HS_STR 66
__global__ __launch_bounds__(256) void ka_fused(const float* __restrict__ x,
                                                const float* __restrict__ wrT,
                                                const float* __restrict__ wspT,
                                                const float* __restrict__ pa,
                                                const float* __restrict__ gamma,
                                                const float* __restrict__ beta,
                                                unsigned short* __restrict__ xnt) {
    __shared__ unsigned short xsT[70 * XS_STR];     // 36120 B  [jj][c] bf16
    __shared__ unsigned short hs_outs[4352];        // 8704 B: hsT[64][66] then outs[256][17]
    __shared__ float ks[GK * 64];                   // 28672 B  [gk][j] f32
    __shared__ float red1[256], red2[256];
    __shared__ float mean_s[16], rstd_s[16];

    int t  = threadIdx.x;
    int b  = blockIdx.x >> 7;
    int l0 = (blockIdx.x & 127) * 64;
    const float* xb = x + (size_t)b * C_DIM * L_DIM;

    // P1: stage xsT[jj][c] = bf16(x[b][c][l0-3+jj]), jj in [0,70)
    for (int i = t; i < 70 * 256; i += 256) {
        unsigned ui = (unsigned)i;
        int c  = ui / 70u;
        int jj = ui - c * 70u;
        int l  = l0 + jj - 3;
        float v = (l >= 0 && l < L_DIM) ? xb[c * L_DIM + l] : 0.f;
        xsT[jj * XS_STR + c] = f2bf(v);
    }
    __syncthreads();

    // P2: h = relu(Wr @ x) -> hsT[jj][r] bf16.  Thread = (rowgroup rg, col jj).
    {
        int rg = __builtin_amdgcn_readfirstlane(t >> 6);   // wave-uniform
        int jj = t & 63;
        const unsigned short* xcol = &xsT[(3 + jj) * XS_STR];
        float acc[16];
#pragma unroll
        for (int i = 0; i < 16; ++i) acc[i] = 0.f;
#pragma unroll 2
        for (int c = 0; c < C_DIM; ++c) {
            float xv = bf2f(xcol[c]);
            const float* wrow = &wrT[c * 64 + rg * 16];
#pragma unroll
            for (int i = 0; i < 16; ++i) acc[i] = fmaf(wrow[i], xv, acc[i]);
        }
        unsigned short* hrow = &hs_outs[jj * HS_STR + rg * 16];
#pragma unroll
        for (int i = 0; i < 16; ++i)
            hrow[i] = f2bf(acc[i] > 0.f ? acc[i] : 0.f);
    }
    __syncthreads();

    // P3: ker = Wsp @ h -> ks[112][64] f32.  Thread = (rowgroup rgk(28), col jj).
    {
        int rgk = __builtin_amdgcn_readfirstlane(t >> 6);
        int jj  = t & 63;
        const unsigned short* hcol = &hs_outs[jj * HS_STR];
        float acc[28];
#pragma unroll
        for (int i = 0; i < 28; ++i) acc[i] = 0.f;
#pragma unroll 2
        for (int r = 0; r < CR; ++r) {
            float hv = bf2f(hcol[r]);
            const float* wrow = &wspT[r * GK + rgk * 28];
#pragma unroll
            for (int i = 0; i < 28; ++i) acc[i] = fmaf(wrow[i], hv, acc[i]);
        }
#pragma unroll
        for (int i = 0; i < 28; ++i) ks[(rgk * 28 + i) * 64 + jj] = acc[i];
    }
    __syncthreads();

    // P4+P5: involution + PReLU + LayerNorm, in 4 quarters of 16 columns.
    int c = t, g = c >> 4;
    float a = pa[0], gam = gamma[c], bet = beta[c];
    unsigned short* outs = hs_outs;     // overlay (hsT dead after P3)
    for (int q = 0; q < 4; ++q) {
        float xwin[22];
#pragma unroll
        for (int i = 0; i < 22; ++i)
            xwin[i] = bf2f(xsT[(q * 16 + i) * XS_STR + c]);
        float acc[16];
#pragma unroll
        for (int jm = 0; jm < 16; ++jm) acc[jm] = 0.f;
#pragma unroll
        for (int k = 0; k < KW; ++k) {
            const float4* kr = (const float4*)&ks[(g * KW + k) * 64 + q * 16];
#pragma unroll
            for (int jc = 0; jc < 4; ++jc) {
                float4 kv = kr[jc];
                acc[jc * 4 + 0] = fmaf(kv.x, xwin[jc * 4 + 0 + k], acc[jc * 4 + 0]);
                acc[jc * 4 + 1] = fmaf(kv.y, xwin[jc * 4 + 1 + k], acc[jc * 4 + 1]);
                acc[jc * 4 + 2] = fmaf(kv.z, xwin[jc * 4 + 2 + k], acc[jc * 4 + 2]);
                acc[jc * 4 + 3] = fmaf(kv.w, xwin[jc * 4 + 3 + k], acc[jc * 4 + 3]);
            }
        }
#pragma unroll
        for (int jm = 0; jm < 16; ++jm)
            acc[jm] = acc[jm] >= 0.f ? acc[jm] : a * acc[jm];

        __syncthreads();                // previous quarter's outs reads done
#pragma unroll
        for (int jm = 0; jm < 16; ++jm)
            outs[c * 17 + jm] = f2bf(acc[jm]);
        __syncthreads();
        {
            int cg = t >> 4, jm = t & 15;
            float s1 = 0.f, s2 = 0.f;
#pragma unroll
            for (int i = 0; i < 16; ++i) {
                float v = bf2f(outs[(cg * 16 + i) * 17 + jm]);
                s1 += v; s2 += v * v;
            }
            red1[t] = s1; red2[t] = s2;
        }
        __syncthreads();
        if (t < 16) {
            float s1 = 0.f, s2 = 0.f;
#pragma unroll
            for (int i = 0; i < 16; ++i) { s1 += red1[i * 16 + t]; s2 += red2[i * 16 + t]; }
            float mu  = s1 * (1.f / 256.f);
            float var = s2 * (1.f / 256.f) - mu * mu;
            mean_s[t] = mu;
            rstd_s[t] = rsqrtf(var + 1e-5f);
        }
        __syncthreads();
#pragma unroll
        for (int jm = 0; jm < 16; ++jm) {
            float v = (acc[jm] - mean_s[jm]) * rstd_s[jm] * gam + bet;
            xnt[((size_t)b * L_DIM + l0 + q * 16 + jm) * C_DIM + c] = f2bf(v);
        }
    }
}

// ---------------------------------------------------------------------------
// KB: [main;skip] = Wcat(512x256) @ outn + residual.  Block = 64 cols x 512
// rows (4 passes of 128). B (xnt) staged once in LDS; A read direct from
// global (W = 256 KB bf16, L2-resident). Stores interleaved with MFMA.
// ---------------------------------------------------------------------------
#define LDX 264
#define SKIP_OFF ((size_t)B_DIM * C_DIM * L_DIM)
__global__ __launch_bounds__(256, 3) void kb_gemm(const unsigned short* __restrict__ wb,
                                                  const unsigned short* __restrict__ xnt,
                                                  const float* __restrict__ x,
                                                  float* __restrict__ out) {
    __shared__ unsigned short Xs[64 * LDX];
    int nb = blockIdx.x;            // 1024 blocks, 64 global cols each
    int col0 = nb * 64;
    int t = threadIdx.x;

    const uint4* xsrc = (const uint4*)(xnt + (size_t)col0 * C_DIM);
#pragma unroll
    for (int i = 0; i < 8; ++i) {
        int cid = t + i * 256;
        int row = cid >> 5, kc = cid & 31;
        *(uint4*)&Xs[row * LDX + kc * 8] = xsrc[cid];
    }
    __syncthreads();

    int w = t >> 6, lane = t & 63;
    int lr = lane & 15, quad = lane >> 4;
    int b = col0 >> 13;             // 64-col tile never crosses batch (8192%64==0)
    int lbase = col0 & 8191;

    for (int mp = 0; mp < 4; ++mp) {
        int r0 = mp * 128 + w * 16;
        short8 a0[8], a1[8];
        const unsigned short* arow0 = wb + (size_t)(r0 + lr) * C_DIM + quad * 8;
        const unsigned short* arow1 = arow0 + 64 * C_DIM;
#pragma unroll
        for (int s = 0; s < 8; ++s) {
            a0[s] = *(const short8*)(arow0 + s * 32);
            a1[s] = *(const short8*)(arow1 + s * 32);
        }
        bool main_half = (mp < 2);
#pragma unroll
        for (int ct = 0; ct < 4; ++ct) {
            floatx4 acc0 = (floatx4){0.f, 0.f, 0.f, 0.f};
            floatx4 acc1 = (floatx4){0.f, 0.f, 0.f, 0.f};
#pragma unroll
            for (int s = 0; s < 8; ++s) {
                short8 bf = *(const short8*)&Xs[(ct * 16 + lr) * LDX + s * 32 + quad * 8];
                acc0 = __builtin_amdgcn_mfma_f32_16x16x32_bf16(a0[s], bf, acc0, 0, 0, 0);
                acc1 = __builtin_amdgcn_mfma_f32_16x16x32_bf16(a1[s], bf, acc1, 0, 0, 0);
            }
            int l = lbase + ct * 16 + lr;
#pragma unroll
            for (int r = 0; r < 4; ++r) {
                int m0 = r0 + quad * 4 + r;       // C/D row = quad*4 + reg
                int m1 = m0 + 64;
                if (main_half) {
                    size_t i0 = ((size_t)b * C_DIM + m0) * L_DIM + l;
                    size_t i1 = ((size_t)b * C_DIM + m1) * L_DIM + l;
                    out[i0] = acc0[r] + x[i0];
                    out[i1] = acc1[r] + x[i1];
                } else {
                    size_t i0 = ((size_t)b * C_DIM + (m0 - 256)) * L_DIM + l;
                    size_t i1 = ((size_t)b * C_DIM + (m1 - 256)) * L_DIM + l;
                    out[SKIP_OFF + i0] = acc0[r];
                    out[SKIP_OFF + i1] = acc1[r];
                }
            }
        }
    }
}

extern "C" void kernel_launch(void* const* d_in, const int* in_sizes, int n_in,
                              void* d_out, int out_size, void* d_ws, size_t ws_size,
                              hipStream_t stream) {
    const float* x     = (const float*)d_in[0];
    const float* w_red = (const float*)d_in[1];
    const float* w_spn = (const float*)d_in[2];
    const float* pa    = (const float*)d_in[3];
    const float* gam   = (const float*)d_in[4];
    const float* bet   = (const float*)d_in[5];
    const float* w_m   = (const float*)d_in[6];
    const float* w_s   = (const float*)d_in[7];
    float* out = (float*)d_out;

    // workspace layout (bytes)
    char* ws = (char*)d_ws;
    unsigned short* wb   = (unsigned short*)(ws);            // 262144 B
    float*          wrT  = (float*)(ws + 262144);            // 65536 B
    float*          wspT = (float*)(ws + 327680);            // 28672 B
    unsigned short* xnt  = (unsigned short*)(ws + 356352);   // 33554432 B

    k0_prep<<<604, 256, 0, stream>>>(w_m, w_s, w_red, w_spn, wb, wrT, wspT);
    ka_fused<<<1024, 256, 0, stream>>>(x, wrT, wspT, pa, gam, bet, xnt);
    kb_gemm<<<1024, 256, 0, stream>>>(wb, xnt, x, out);
}

// Round 3
// 276.397 us; speedup vs baseline: 1.8726x; 1.8726x over previous
//
#include <hip/hip_runtime.h>
#include <stdint.h>

#define C_DIM 256
#define L_DIM 8192
#define B_DIM 8
#define SKIP_OFF ((size_t)B_DIM * C_DIM * L_DIM)

using short8  = __attribute__((ext_vector_type(8))) short;
using floatx4 = __attribute__((ext_vector_type(4))) float;
typedef unsigned short ushort_t;

__device__ __forceinline__ ushort_t f2bf(float f) {
    union { float f; uint32_t u; } v; v.f = f;
    uint32_t u = v.u;
    return (ushort_t)((u + 0x7fff + ((u >> 16) & 1)) >> 16);
}
__device__ __forceinline__ float bf2f(ushort_t h) {
    union { uint32_t u; float f; } v; v.u = ((uint32_t)h) << 16;
    return v.f;
}

// frag-linear 64x256 bf16 tile: element (l, c) at
// [l>>4][c>>5][l&15][(c>>3)&3][c&7]  -> B-frag reads are lane-linear ds_read_b128
__device__ __forceinline__ int fragaddr(int l, int c) {
    return ((((l >> 4) * 8 + (c >> 5)) * 16 + (l & 15)) * 4 + ((c >> 3) & 3)) * 8 + (c & 7);
}

// ---------------------------------------------------------------------------
// K0: weight prep: wb bf16[512][256] = [w_main;w_skip]; wrb bf16[64][256];
// wsb bf16[128][64] (= w_span zero-padded from 112 to 128 rows)
// ---------------------------------------------------------------------------
__global__ __launch_bounds__(256) void k0_prep(const float* __restrict__ wm,
                                               const float* __restrict__ wk,
                                               const float* __restrict__ wr,
                                               const float* __restrict__ wsp,
                                               ushort_t* __restrict__ wb,
                                               ushort_t* __restrict__ wrb,
                                               ushort_t* __restrict__ wsb) {
    int i = blockIdx.x * 256 + threadIdx.x;
    if (i < 65536) wb[i] = f2bf(wm[i]);
    else if (i < 131072) wb[i] = f2bf(wk[i - 65536]);
    else if (i < 147456) wrb[i - 131072] = f2bf(wr[i - 131072]);
    else if (i < 155648) {
        int j = i - 147456;
        int r = j >> 6, cc = j & 63;
        wsb[j] = (r < 112) ? f2bf(wsp[r * 64 + cc]) : (ushort_t)0;
    }
}

// ---------------------------------------------------------------------------
// KF: per (b, 64-l tile): x fp32 -> bf16 frag LDS; export xbT (c-contig);
// h = relu(Wr@x) via MFMA; ker = Wsp@h via MFMA; export kb.
// ---------------------------------------------------------------------------
#define KST_STR 72
__global__ __launch_bounds__(256) void kf_front(const float* __restrict__ x,
                                                const ushort_t* __restrict__ wrb,
                                                const ushort_t* __restrict__ wsb,
                                                ushort_t* __restrict__ xbT,
                                                ushort_t* __restrict__ kb) {
    __shared__ ushort_t xsF[16384];                 // 32768 B frag-linear x tile
    __shared__ ushort_t hTF[4096];                  // 8192 B  frag-linear h (64x64)
    ushort_t* kst = xsF;                            // overlay: [112][72] after xsF dead

    int t = threadIdx.x;
    int b = blockIdx.x >> 7, l0 = (blockIdx.x & 127) * 64;
    const float* xb = x + (size_t)b * C_DIM * L_DIM;

    // P1: load fp32 (coalesced float4 along l), cvt, scatter to frag LDS
    {
        int lo = (t & 15) * 4;
        int cbase = t >> 4;
#pragma unroll
        for (int j = 0; j < 16; ++j) {
            int c = cbase + j * 16;
            float4 v = *(const float4*)&xb[(size_t)c * L_DIM + l0 + lo];
            xsF[fragaddr(lo + 0, c)] = f2bf(v.x);
            xsF[fragaddr(lo + 1, c)] = f2bf(v.y);
            xsF[fragaddr(lo + 2, c)] = f2bf(v.z);
            xsF[fragaddr(lo + 3, c)] = f2bf(v.w);
        }
    }
    __syncthreads();

    // P2: export xbT[(b*L+l)*256 + c] (coalesced 512B rows)
    {
        size_t base = ((size_t)b * L_DIM + l0) * C_DIM;
#pragma unroll
        for (int ii = 0; ii < 8; ++ii) {
            int i = t + ii * 256;
            int l = i >> 5, ch = i & 31;
            uint4 v = *(const uint4*)&xsF[fragaddr(l, ch * 8)];
            *(uint4*)&xbT[base + (size_t)l * C_DIM + ch * 8] = v;
        }
    }

    int w = t >> 6, lane = t & 63, lr = lane & 15, quad = lane >> 4;

    // P3: h-GEMM M=64,K=256,N=64. Wave w -> rows w*16..+15.
    {
        short8 af[8];
#pragma unroll
        for (int s = 0; s < 8; ++s)
            af[s] = *(const short8*)&wrb[(w * 16 + lr) * 256 + s * 32 + quad * 8];
#pragma unroll
        for (int nt = 0; nt < 4; ++nt) {
            floatx4 acc = {0.f, 0.f, 0.f, 0.f};
#pragma unroll
            for (int s = 0; s < 8; ++s) {
                short8 bf = *(const short8*)&xsF[(((nt * 8 + s) * 16 + lr) * 4 + quad) * 8];
                acc = __builtin_amdgcn_mfma_f32_16x16x32_bf16(af[s], bf, acc, 0, 0, 0);
            }
            // C/D: n = nt*16+lr, r = w*16 + quad*4 + reg. ReLU, write h frag-linear.
            int r0 = w * 16 + quad * 4;
            int sK = r0 >> 5, quadK = (r0 >> 3) & 3, j0 = r0 & 7;
            ushort4 hv;
            hv.x = f2bf(fmaxf(acc[0], 0.f));
            hv.y = f2bf(fmaxf(acc[1], 0.f));
            hv.z = f2bf(fmaxf(acc[2], 0.f));
            hv.w = f2bf(fmaxf(acc[3], 0.f));
            *(ushort4*)&hTF[(((nt * 2 + sK) * 16 + lr) * 4 + quadK) * 8 + j0] = hv;
        }
    }
    __syncthreads();

    // P4: ker-GEMM M=128(pad),K=64,N=64. Wave w -> m-tiles {2w, 2w+1}; skip mt=7 (pad).
#pragma unroll
    for (int mi = 0; mi < 2; ++mi) {
        int mt = w * 2 + mi;
        if (mt == 7) break;
        short8 aw[2];
#pragma unroll
        for (int s = 0; s < 2; ++s)
            aw[s] = *(const short8*)&wsb[(mt * 16 + lr) * 64 + s * 32 + quad * 8];
#pragma unroll
        for (int nt = 0; nt < 4; ++nt) {
            floatx4 acc = {0.f, 0.f, 0.f, 0.f};
#pragma unroll
            for (int s = 0; s < 2; ++s) {
                short8 bf = *(const short8*)&hTF[(((nt * 2 + s) * 16 + lr) * 4 + quad) * 8];
                acc = __builtin_amdgcn_mfma_f32_16x16x32_bf16(aw[s], bf, acc, 0, 0, 0);
            }
            int r0 = mt * 16 + quad * 4;
            int n  = nt * 16 + lr;
#pragma unroll
            for (int r = 0; r < 4; ++r)
                kst[(r0 + r) * KST_STR + n] = f2bf(acc[r]);
        }
    }
    __syncthreads();

    // P5: export kb[b][r][l] coalesced
#pragma unroll
    for (int ii = 0; ii < 4; ++ii) {
        int i = t + ii * 256;
        if (i < 896) {
            int r = i >> 3, ch = i & 7;
            uint4 v = *(const uint4*)&kst[r * KST_STR + ch * 8];
            *(uint4*)&kb[((size_t)b * 112 + r) * L_DIM + l0 + ch * 8] = v;
        }
    }
}

// ---------------------------------------------------------------------------
// KG: per (b, 64-l tile): involution (xbT coalesced global, ker LDS) -> PReLU
// -> LayerNorm -> normalized tile in frag LDS -> 512x256 MFMA GEMM -> out.
// ---------------------------------------------------------------------------
#define KS_STR 72
__global__ __launch_bounds__(256) void kg_back(const ushort_t* __restrict__ xbT,
                                               const ushort_t* __restrict__ kb,
                                               const ushort_t* __restrict__ wb,
                                               const float* __restrict__ x,
                                               const float* __restrict__ pa,
                                               const float* __restrict__ gamma,
                                               const float* __restrict__ beta,
                                               float* __restrict__ out) {
    __shared__ ushort_t ks[112 * KS_STR];       // 16128 B
    __shared__ ushort_t xnF[16384];             // 32768 B frag-linear normalized tile
    __shared__ float red1[256], red2[256];
    __shared__ float mean_s[64], rstd_s[64];

    int t = threadIdx.x;
    int b = blockIdx.x >> 7, l0 = (blockIdx.x & 127) * 64;

    // stage ker tile
#pragma unroll
    for (int ii = 0; ii < 4; ++ii) {
        int i = t + ii * 256;
        if (i < 896) {
            int r = i >> 3, ch = i & 7;
            uint4 v = *(const uint4*)&kb[((size_t)b * 112 + r) * L_DIM + l0 + ch * 8];
            *(uint4*)&ks[r * KS_STR + ch * 8] = v;
        }
    }
    __syncthreads();

    int c = t, g = c >> 4;
    float aslope = pa[0], gam = gamma[c], bet = beta[c];
    const size_t xrow = (size_t)b * L_DIM * C_DIM;

    for (int hp = 0; hp < 2; ++hp) {
        int lbase = l0 + hp * 32;
        float xwin[38];
#pragma unroll
        for (int jj = 0; jj < 38; ++jj) {
            int l = lbase - 3 + jj;
            xwin[jj] = (l >= 0 && l < L_DIM) ? bf2f(xbT[xrow + (size_t)l * C_DIM + c]) : 0.f;
        }
        float acc[32];
#pragma unroll
        for (int j = 0; j < 32; ++j) acc[j] = 0.f;
#pragma unroll
        for (int k = 0; k < 7; ++k) {
            const ushort_t* krow = &ks[(g * 7 + k) * KS_STR + hp * 32];
#pragma unroll
            for (int ch = 0; ch < 4; ++ch) {
                ushort4 kp0 = *(const ushort4*)&krow[ch * 8];
                ushort4 kp1 = *(const ushort4*)&krow[ch * 8 + 4];
                float kv0 = bf2f(kp0.x), kv1 = bf2f(kp0.y), kv2 = bf2f(kp0.z), kv3 = bf2f(kp0.w);
                float kv4 = bf2f(kp1.x), kv5 = bf2f(kp1.y), kv6 = bf2f(kp1.z), kv7 = bf2f(kp1.w);
                acc[ch*8+0] = fmaf(kv0, xwin[ch*8 + 0 + k], acc[ch*8+0]);
                acc[ch*8+1] = fmaf(kv1, xwin[ch*8 + 1 + k], acc[ch*8+1]);
                acc[ch*8+2] = fmaf(kv2, xwin[ch*8 + 2 + k], acc[ch*8+2]);
                acc[ch*8+3] = fmaf(kv3, xwin[ch*8 + 3 + k], acc[ch*8+3]);
                acc[ch*8+4] = fmaf(kv4, xwin[ch*8 + 4 + k], acc[ch*8+4]);
                acc[ch*8+5] = fmaf(kv5, xwin[ch*8 + 5 + k], acc[ch*8+5]);
                acc[ch*8+6] = fmaf(kv6, xwin[ch*8 + 6 + k], acc[ch*8+6]);
                acc[ch*8+7] = fmaf(kv7, xwin[ch*8 + 7 + k], acc[ch*8+7]);
            }
        }
        // PReLU + pre-norm bf16 into xnF (stats read it back)
#pragma unroll
        for (int j = 0; j < 32; ++j) {
            acc[j] = acc[j] >= 0.f ? acc[j] : aslope * acc[j];
            xnF[fragaddr(hp * 32 + j, c)] = f2bf(acc[j]);
        }
        __syncthreads();
        {
            int lloc = hp * 32 + (t >> 3), seg = t & 7;
            float s1 = 0.f, s2 = 0.f;
#pragma unroll
            for (int q = 0; q < 4; ++q) {
                ushort4 v0 = *(const ushort4*)&xnF[fragaddr(lloc, seg * 32 + q * 8)];
                ushort4 v1 = *(const ushort4*)&xnF[fragaddr(lloc, seg * 32 + q * 8 + 4)];
                float f0 = bf2f(v0.x), f1 = bf2f(v0.y), f2v = bf2f(v0.z), f3 = bf2f(v0.w);
                float f4 = bf2f(v1.x), f5 = bf2f(v1.y), f6 = bf2f(v1.z), f7 = bf2f(v1.w);
                s1 += ((f0 + f1) + (f2v + f3)) + ((f4 + f5) + (f6 + f7));
                s2 += f0*f0 + f1*f1 + f2v*f2v + f3*f3 + f4*f4 + f5*f5 + f6*f6 + f7*f7;
            }
            red1[t] = s1; red2[t] = s2;
        }
        __syncthreads();
        if (t < 32) {
            float s1 = 0.f, s2 = 0.f;
#pragma unroll
            for (int i = 0; i < 8; ++i) { s1 += red1[t * 8 + i]; s2 += red2[t * 8 + i]; }
            float mu  = s1 * (1.f / 256.f);
            float var = s2 * (1.f / 256.f) - mu * mu;
            mean_s[hp * 32 + t] = mu;
            rstd_s[hp * 32 + t] = rsqrtf(var + 1e-5f);
        }
        __syncthreads();
#pragma unroll
        for (int j = 0; j < 32; ++j) {
            float v = (acc[j] - mean_s[hp * 32 + j]) * rstd_s[hp * 32 + j] * gam + bet;
            xnF[fragaddr(hp * 32 + j, c)] = f2bf(v);
        }
        __syncthreads();
    }

    // phase B: [main;skip](512x256) @ xn(256x64); wave w -> rows [w*128,(w+1)*128)
    int w = t >> 6, lane = t & 63, lr = lane & 15, quad = lane >> 4;
#pragma unroll
    for (int mi = 0; mi < 8; ++mi) {
        int mt = w * 8 + mi;
        const ushort_t* arow = wb + (size_t)(mt * 16 + lr) * 256 + quad * 8;
        short8 a[8];
#pragma unroll
        for (int s = 0; s < 8; ++s) a[s] = *(const short8*)(arow + s * 32);
#pragma unroll
        for (int nt = 0; nt < 4; ++nt) {
            floatx4 acc = {0.f, 0.f, 0.f, 0.f};
#pragma unroll
            for (int s = 0; s < 8; ++s) {
                short8 bfr = *(const short8*)&xnF[(((nt * 8 + s) * 16 + lr) * 4 + quad) * 8];
                acc = __builtin_amdgcn_mfma_f32_16x16x32_bf16(a[s], bfr, acc, 0, 0, 0);
            }
            int m = mt * 16 + quad * 4;
            int l = l0 + nt * 16 + lr;
            if (mt < 16) {
                size_t base = ((size_t)b * C_DIM + m) * L_DIM + l;
#pragma unroll
                for (int r = 0; r < 4; ++r)
                    out[base + (size_t)r * L_DIM] = acc[r] + x[base + (size_t)r * L_DIM];
            } else {
                size_t base = SKIP_OFF + ((size_t)b * C_DIM + (m - 256)) * L_DIM + l;
#pragma unroll
                for (int r = 0; r < 4; ++r)
                    out[base + (size_t)r * L_DIM] = acc[r];
            }
        }
    }
}

extern "C" void kernel_launch(void* const* d_in, const int* in_sizes, int n_in,
                              void* d_out, int out_size, void* d_ws, size_t ws_size,
                              hipStream_t stream) {
    const float* x     = (const float*)d_in[0];
    const float* w_red = (const float*)d_in[1];
    const float* w_spn = (const float*)d_in[2];
    const float* pa    = (const float*)d_in[3];
    const float* gam   = (const float*)d_in[4];
    const float* bet   = (const float*)d_in[5];
    const float* w_m   = (const float*)d_in[6];
    const float* w_s   = (const float*)d_in[7];
    float* out = (float*)d_out;

    char* ws = (char*)d_ws;
    ushort_t* wb  = (ushort_t*)(ws);                       // 262144 B
    ushort_t* wrb = (ushort_t*)(ws + 262144);              // 32768 B
    ushort_t* wsb = (ushort_t*)(ws + 295040 - 128);        // 16384 B (at 294912)
    ushort_t* xbT = (ushort_t*)(ws + 311296);              // 33554432 B
    ushort_t* kb  = (ushort_t*)(ws + 311296 + 33554432);   // 14680064 B

    k0_prep<<<608, 256, 0, stream>>>(w_m, w_s, w_red, w_spn, wb, wrb, wsb);
    kf_front<<<1024, 256, 0, stream>>>(x, wrb, wsb, xbT, kb);
    kg_back<<<1024, 256, 0, stream>>>(xbT, kb, wb, x, pa, gam, bet, out);
}